// Round 7
// baseline (200.815 us; speedup 1.0000x reference)
//
#include <hip/hip_runtime.h>
#include <hip/hip_bf16.h>
#include <stdint.h>

// scores[b,q,k] = dot(Q[b,q,:],K[b,k,:]) / (max(|Qrow|,eps)*max(|Krow|,eps)); mask==0 -> -1e9
// B=4, Sq=Sk=2048, D=1024, fp32 in/out.
//
// R13: single fused workspace-free kernel. R12 post-mortem: occupancy 33->62%
//      with dur 52.9->56.6 -> TLP not binding; GEMM schedule axis exhausted at
//      ~53us (six variants, MfmaUtil pinned 21-25%). Accounting: total =
//      gemm + convert(~17us) + ~90us fixed; fixed block likely includes 67MB
//      workspace re-poison + extra dispatch overhead. Lever: eliminate the
//      second kernel and ALL d_ws use.
//      Fusion: R10 gemm core (128^2 tile, BK=64, 4 waves, 32x32x16 MFMA,
//      chunk-XOR swizzle, XCD clustering) with reg-staging from fp32:
//      load f32x4 -> pack_bf16 -> swizzled ds_write_b128 (write-side pos =
//      read-side pos = c^(r&7), rule 21 involution). Row/col norms computed
//      in-register during staging (thread covers cols [qt*16,+16) mod 64 of
//      rows rS,rS+64 over the K-loop -> 4-lane shfl reduce -> invA/invB LDS).
//      VALU tax ~6.7us/SIMD < MFMA 13.7us shadow (m114 dual-issue).
constexpr int B_  = 4;
constexpr int SQ  = 2048;
constexpr int SK  = 2048;
constexpr int D_  = 1024;
constexpr int BM  = 128;
constexpr int BN  = 128;
constexpr int BK  = 64;    // bf16 K-tile: 128 B rows = 8 x 16B chunks

typedef __attribute__((ext_vector_type(8)))  short    short8;
typedef __attribute__((ext_vector_type(4)))  float    f32x4;
typedef __attribute__((ext_vector_type(16))) float    f32x16;
typedef __attribute__((ext_vector_type(4)))  unsigned uint4v;
typedef unsigned int u32;

__device__ inline unsigned pack_bf16(float lo, float hi) {
  union { float f; unsigned u; } a, b;
  a.f = lo; b.f = hi;
  return __builtin_amdgcn_perm(b.u, a.u, 0x07060302u);
}

__device__ inline float dot4(f32x4 v) {
  return v.x*v.x + v.y*v.y + v.z*v.z + v.w*v.w;
}

// ---------------- Fused: convert + norms + GEMM, no workspace ----------------
// LDS row r (128 B = 8 x 16B chunks): position p holds global chunk p ^ (r&7).
// Staging (reg): thread tid -> rows rS=tid>>2 and rS+64, col quarter qt=tid&3
//   (16 fp32 = 2 bf16-chunks c=2qt,2qt+1). Write chunk c at pos c^(rS&7)
//   ((rS+64)&7 == rS&7). Write sweep: 16 rows x 4 qt -> 8 pos values x 8 lanes
//   = uniform 8 words/bank (inherent b128 minimum).
// Fragment read (32x32x16): chunk c = 2*s+h at pos c^(r&7) — identical to R10.
// Norms: ss accumulated from fp32 values pre-rounding (matches ref);
//   thread's col coverage over K-loop = [qt*16,+16) mod 64 = disjoint quarter;
//   reduce over qt group via shfl_xor(1),(2); lane qt==0 writes invA/invB.
__global__ __launch_bounds__(256, 4) void ca_fused(
    const float* __restrict__ Q,
    const float* __restrict__ Km,
    const int*   __restrict__ mask,
    float*       __restrict__ out)
{
  __shared__ __align__(16) unsigned short As[BM * BK];   // 16 KB
  __shared__ __align__(16) unsigned short Bs[BN * BK];   // 16 KB
  __shared__ float invA[BM];
  __shared__ float invB[BN];

  const int tid  = threadIdx.x;
  const int lane = tid & 63;
  const int w    = tid >> 6;

  // XCD-clustered decode (R10): 16 squares of 8x8 tiles; xcd = lid&7 owns 2.
  const int lid = blockIdx.x;           // 0..1023
  const int xcd = lid & 7;
  const int idx = lid >> 3;             // 0..127
  const int sq  = xcd * 2 + (idx >> 6); // 0..15
  const int b   = sq >> 2;              // batch
  const int qd  = sq & 3;               // quadrant of the 16x16 tile grid
  const int ty  = (qd >> 1) * 8 + ((idx >> 3) & 7);
  const int tx  = (qd & 1) * 8 + (idx & 7);
  const int tm0 = ty * BM;
  const int tn0 = tx * BN;

  // staging coords
  const int rS = tid >> 2;              // 0..63 (pass 1 adds 64)
  const int qt = tid & 3;               // col quarter (16 fp32)
  const float* qp0 = Q  + ((size_t)b * SQ + tm0 + rS     ) * D_ + qt * 16;
  const float* qp1 = Q  + ((size_t)b * SQ + tm0 + rS + 64) * D_ + qt * 16;
  const float* kp0 = Km + ((size_t)b * SK + tn0 + rS     ) * D_ + qt * 16;
  const float* kp1 = Km + ((size_t)b * SK + tn0 + rS + 64) * D_ + qt * 16;
  unsigned short* wA0 = &As[(size_t)rS * BK];
  unsigned short* wA1 = &As[(size_t)(rS + 64) * BK];
  unsigned short* wB0 = &Bs[(size_t)rS * BK];
  unsigned short* wB1 = &Bs[(size_t)(rS + 64) * BK];
  const int pc0 = ((2 * qt)     ^ (rS & 7)) * 8;   // shorts offset of chunk
  const int pc1 = ((2 * qt + 1) ^ (rS & 7)) * 8;

  f32x16 acc[2][2];
  #pragma unroll
  for (int i = 0; i < 2; ++i)
    #pragma unroll
    for (int j = 0; j < 2; ++j)
      #pragma unroll
      for (int r = 0; r < 16; ++r) acc[i][j][r] = 0.0f;

  float sQ0 = 0.0f, sQ1 = 0.0f, sK0 = 0.0f, sK1 = 0.0f;

  const int wm = (w >> 1) * 64;
  const int wn = (w & 1) * 64;
  const int ln = lane & 31;    // 32x32 fragment row/col
  const int h  = lane >> 5;    // k-half select

  for (int k0 = 0; k0 < D_; k0 += BK) {
    // ---- A loads (issue before guard barrier so latency overlaps the sync) ----
    f32x4 a0v[4], a1v[4];
    #pragma unroll
    for (int i = 0; i < 4; ++i) a0v[i] = *(const f32x4*)(qp0 + 4 * i);
    #pragma unroll
    for (int i = 0; i < 4; ++i) a1v[i] = *(const f32x4*)(qp1 + 4 * i);
    qp0 += BK; qp1 += BK;

    __syncthreads();   // guard: all fragment reads of previous tile done

    // ---- pack + write A, accumulate Q row norms ----
    {
      unsigned p0[8], p1[8];
      #pragma unroll
      for (int i = 0; i < 4; ++i) {
        p0[2*i]   = pack_bf16(a0v[i].x, a0v[i].y);
        p0[2*i+1] = pack_bf16(a0v[i].z, a0v[i].w);
        p1[2*i]   = pack_bf16(a1v[i].x, a1v[i].y);
        p1[2*i+1] = pack_bf16(a1v[i].z, a1v[i].w);
        sQ0 += dot4(a0v[i]);
        sQ1 += dot4(a1v[i]);
      }
      uint4v u00 = {p0[0], p0[1], p0[2], p0[3]};
      uint4v u01 = {p0[4], p0[5], p0[6], p0[7]};
      uint4v u10 = {p1[0], p1[1], p1[2], p1[3]};
      uint4v u11 = {p1[4], p1[5], p1[6], p1[7]};
      *(uint4v*)(wA0 + pc0) = u00;
      *(uint4v*)(wA0 + pc1) = u01;
      *(uint4v*)(wA1 + pc0) = u10;
      *(uint4v*)(wA1 + pc1) = u11;
    }

    // ---- B loads + pack + write, accumulate K row norms ----
    {
      f32x4 b0v[4], b1v[4];
      #pragma unroll
      for (int i = 0; i < 4; ++i) b0v[i] = *(const f32x4*)(kp0 + 4 * i);
      #pragma unroll
      for (int i = 0; i < 4; ++i) b1v[i] = *(const f32x4*)(kp1 + 4 * i);
      kp0 += BK; kp1 += BK;
      unsigned p0[8], p1[8];
      #pragma unroll
      for (int i = 0; i < 4; ++i) {
        p0[2*i]   = pack_bf16(b0v[i].x, b0v[i].y);
        p0[2*i+1] = pack_bf16(b0v[i].z, b0v[i].w);
        p1[2*i]   = pack_bf16(b1v[i].x, b1v[i].y);
        p1[2*i+1] = pack_bf16(b1v[i].z, b1v[i].w);
        sK0 += dot4(b0v[i]);
        sK1 += dot4(b1v[i]);
      }
      uint4v u00 = {p0[0], p0[1], p0[2], p0[3]};
      uint4v u01 = {p0[4], p0[5], p0[6], p0[7]};
      uint4v u10 = {p1[0], p1[1], p1[2], p1[3]};
      uint4v u11 = {p1[4], p1[5], p1[6], p1[7]};
      *(uint4v*)(wB0 + pc0) = u00;
      *(uint4v*)(wB0 + pc1) = u01;
      *(uint4v*)(wB1 + pc0) = u10;
      *(uint4v*)(wB1 + pc1) = u11;
    }

    __syncthreads();   // staged tile visible

    // ---- compute: four k-steps of 16 (R10, unchanged) ----
    #pragma unroll
    for (int s = 0; s < 4; ++s) {
      const int c = 2 * s + h;      // 16B chunk holding k = s*16 + h*8 .. +7
      const int ra0 = wm + ln, ra1 = wm + 32 + ln;
      const int rb0 = wn + ln, rb1 = wn + 32 + ln;
      short8 a0 = *(const short8*)&As[(size_t)ra0 * BK + (size_t)((c ^ (ra0 & 7)) * 8)];
      short8 a1 = *(const short8*)&As[(size_t)ra1 * BK + (size_t)((c ^ (ra1 & 7)) * 8)];
      short8 b0 = *(const short8*)&Bs[(size_t)rb0 * BK + (size_t)((c ^ (rb0 & 7)) * 8)];
      short8 b1 = *(const short8*)&Bs[(size_t)rb1 * BK + (size_t)((c ^ (rb1 & 7)) * 8)];
      acc[0][0] = __builtin_amdgcn_mfma_f32_32x32x16_bf16(a0, b0, acc[0][0], 0, 0, 0);
      acc[0][1] = __builtin_amdgcn_mfma_f32_32x32x16_bf16(a0, b1, acc[0][1], 0, 0, 0);
      acc[1][0] = __builtin_amdgcn_mfma_f32_32x32x16_bf16(a1, b0, acc[1][0], 0, 0, 0);
      acc[1][1] = __builtin_amdgcn_mfma_f32_32x32x16_bf16(a1, b1, acc[1][1], 0, 0, 0);
    }
  }

  // ---- norms: reduce over qt group (lanes differing in bits 0,1) ----
  {
    float t;
    t = sQ0 + __shfl_xor(sQ0, 1); sQ0 = t + __shfl_xor(t, 2);
    t = sQ1 + __shfl_xor(sQ1, 1); sQ1 = t + __shfl_xor(t, 2);
    t = sK0 + __shfl_xor(sK0, 1); sK0 = t + __shfl_xor(t, 2);
    t = sK1 + __shfl_xor(sK1, 1); sK1 = t + __shfl_xor(t, 2);
    if (qt == 0) {
      invA[rS]      = 1.0f / fmaxf(sqrtf(sQ0), 1e-8f);
      invA[rS + 64] = 1.0f / fmaxf(sqrtf(sQ1), 1e-8f);
      invB[rS]      = 1.0f / fmaxf(sqrtf(sK0), 1e-8f);
      invB[rS + 64] = 1.0f / fmaxf(sqrtf(sK1), 1e-8f);
    }
  }
  __syncthreads();

  // Epilogue: 32x32 C/D layout col=lane&31, row=(reg&3)+8*(reg>>2)+4*(lane>>5) [m74/m101].
  #pragma unroll
  for (int tj = 0; tj < 2; ++tj) {
    const int lc = wn + tj * 32 + ln;
    const int gc = tn0 + lc;
    const int mk = mask[b * SK + gc];
    const float ibv = invB[lc];
    #pragma unroll
    for (int ti = 0; ti < 2; ++ti) {
      #pragma unroll
      for (int reg = 0; reg < 16; ++reg) {
        const int row = wm + ti * 32 + (reg & 3) + 8 * (reg >> 2) + 4 * h;
        const float iav = invA[row];
        float v = mk ? acc[ti][tj][reg] * iav * ibv : -1000000000.0f;
        out[((size_t)b * SQ + tm0 + row) * SK + gc] = v;
      }
    }
  }
}

extern "C" void kernel_launch(void* const* d_in, const int* in_sizes, int n_in,
                              void* d_out, int out_size, void* d_ws, size_t ws_size,
                              hipStream_t stream) {
  const float* Q    = (const float*)d_in[0];
  const float* Km   = (const float*)d_in[1];
  const int*   mask = (const int*)d_in[2];
  float*       out  = (float*)d_out;
  (void)d_ws; (void)ws_size;   // workspace-free by design (R13)

  ca_fused<<<dim3(1024), dim3(256), 0, stream>>>(Q, Km, mask, out);
}